// Round 1
// baseline (151.375 us; speedup 1.0000x reference)
//
#include <hip/hip_runtime.h>

#define N_   2
#define C_   256
#define H_   55
#define W_   128
#define HW_  (H_ * W_)      // 7040
#define NPIX (N_ * HW_)     // 14080

#define OFF_CV  0
#define OFF_VAL (NPIX * 25)          // 352000
#define OFF_XY  (OFF_VAL + NPIX)     // 366080

// ---------------------------------------------------------------------------
// Transpose [C, HW] -> [HW, C] per (tensor, n).  blockIdx.z: bit0 = n, bit1 = tensor
// ---------------------------------------------------------------------------
__global__ __launch_bounds__(256) void transpose_kernel(const float* __restrict__ f1,
                                                        const float* __restrict__ f2,
                                                        float* __restrict__ f1t,
                                                        float* __restrict__ f2t) {
    __shared__ float tile[64][65];
    const int z = blockIdx.z;
    const int n = z & 1;
    const float* __restrict__ src = (z & 2) ? f2 : f1;
    float* __restrict__ dst = (z & 2) ? f2t : f1t;
    src += (size_t)n * C_ * HW_;
    dst += (size_t)n * C_ * HW_;

    const int p0 = blockIdx.x * 64;   // HW_ = 110 * 64, exact
    const int c0 = blockIdx.y * 64;   // C_  = 4 * 64, exact
    const int tx  = threadIdx.x & 63;
    const int ty0 = threadIdx.x >> 6;

    #pragma unroll
    for (int r = ty0; r < 64; r += 4)
        tile[r][tx] = src[(size_t)(c0 + r) * HW_ + (p0 + tx)];
    __syncthreads();
    #pragma unroll
    for (int r = ty0; r < 64; r += 4)
        dst[(size_t)(p0 + r) * C_ + (c0 + tx)] = tile[tx][r];
}

// ---------------------------------------------------------------------------
// Main kernel: 1 wave per output pixel. Lanes 0..35 each compute one D(y,x)
// dot over C=256; lanes 0..24 blend to cv; shuffle-reduce for WTA.
// ---------------------------------------------------------------------------
__global__ __launch_bounds__(256) void costvol_kernel(const float* __restrict__ flow,
                                                      const float* __restrict__ f1t,
                                                      const float* __restrict__ f2t,
                                                      float* __restrict__ out) {
    __shared__ float f1sh[4][C_];
    __shared__ float Dsh[4][36];

    const int wv   = threadIdx.x >> 6;
    const int lane = threadIdx.x & 63;
    const int pix  = blockIdx.x * 4 + wv;     // grid sized exactly: NPIX/4 blocks
    const int n    = pix / HW_;
    const int rem  = pix - n * HW_;
    const int h    = rem >> 7;                // W_ = 128
    const int w    = rem & (W_ - 1);

    // Stage this pixel's f1 row (256 floats) into LDS — one coalesced dwordx4/wave.
    ((float4*)f1sh[wv])[lane] = ((const float4*)(f1t + (size_t)pix * C_))[lane];

    const float fx = flow[((size_t)(n * 2 + 0) * H_ + h) * W_ + w];
    const float fy = flow[((size_t)(n * 2 + 1) * H_ + h) * W_ + w];
    const float cx = (float)w + fx;
    const float cy = (float)h + fy;
    const float x0f = floorf(cx), y0f = floorf(cy);
    const float wx = cx - x0f,   wy = cy - y0f;
    const int ix0 = (int)x0f,    iy0 = (int)y0f;

    __syncthreads();   // f1sh visible

    float D = 0.f;
    if (lane < 36) {
        const int ly = lane / 6, lx = lane - ly * 6;
        const int sy = iy0 - 2 + ly;
        const int sx = ix0 - 2 + lx;
        if (sy >= 0 && sy < H_ && sx >= 0 && sx < W_) {
            const float4* __restrict__ a = (const float4*)f1sh[wv];
            const float4* __restrict__ b =
                (const float4*)(f2t + ((size_t)(n * H_ + sy) * W_ + sx) * C_);
            float acc0 = 0.f, acc1 = 0.f, acc2 = 0.f, acc3 = 0.f;
            #pragma unroll 8
            for (int q = 0; q < C_ / 4; ++q) {
                const float4 av = a[q];
                const float4 bv = b[q];
                acc0 += av.x * bv.x;
                acc1 += av.y * bv.y;
                acc2 += av.z * bv.z;
                acc3 += av.w * bv.w;
            }
            D = (acc0 + acc1) + (acc2 + acc3);
        }
        Dsh[wv][lane] = D;   // 0 for out-of-bounds samples
    }
    __syncthreads();   // Dsh visible within wave

    float cv = 0.f;
    if (lane < 25) {
        const int i = lane / 5, j = lane - i * 5;      // i -> dy, j -> dx
        const float D00 = Dsh[wv][i * 6 + j];
        const float D01 = Dsh[wv][i * 6 + j + 1];
        const float D10 = Dsh[wv][i * 6 + j + 6];
        const float D11 = Dsh[wv][i * 6 + j + 7];
        cv = (1.f - wx) * (1.f - wy) * D00 + wx * (1.f - wy) * D01
           + (1.f - wx) * wy * D10 + wx * wy * D11;
        out[OFF_CV + (size_t)pix * 25 + lane] = cv;
    }

    // WTA: max with first-occurrence tie-break (matches np/jnp argmax).
    float v  = (lane < 25) ? cv : -3.4e38f;
    int  idx = (lane < 25) ? lane : 25;
    #pragma unroll
    for (int off = 16; off >= 1; off >>= 1) {
        const float v2 = __shfl_down(v, off, 32);
        const int   i2 = __shfl_down(idx, off, 32);
        if (v2 > v || (v2 == v && i2 < idx)) { v = v2; idx = i2; }
    }
    if (lane == 0) {
        out[OFF_VAL + pix] = v;
        out[OFF_XY + pix]        = (float)(idx % 5);   // x
        out[OFF_XY + NPIX + pix] = (float)(idx / 5);   // y
    }
}

// ---------------------------------------------------------------------------
extern "C" void kernel_launch(void* const* d_in, const int* in_sizes, int n_in,
                              void* d_out, int out_size, void* d_ws, size_t ws_size,
                              hipStream_t stream) {
    const float* flow = (const float*)d_in[0];
    const float* f1   = (const float*)d_in[1];
    const float* f2   = (const float*)d_in[2];
    float* out = (float*)d_out;

    float* f1t = (float*)d_ws;                       // [N, HW, C]
    float* f2t = f1t + (size_t)N_ * HW_ * C_;        // [N, HW, C]

    transpose_kernel<<<dim3(HW_ / 64, C_ / 64, 4), 256, 0, stream>>>(f1, f2, f1t, f2t);
    costvol_kernel<<<dim3(NPIX / 4), 256, 0, stream>>>(flow, f1t, f2t, out);
}

// Round 2
// 115.558 us; speedup vs baseline: 1.3099x; 1.3099x over previous
//
#include <hip/hip_runtime.h>

#define N_   2
#define C_   256
#define H_   55
#define W_   128
#define HW_  (H_ * W_)      // 7040
#define NPIX (N_ * HW_)     // 14080

#define OFF_CV  0
#define OFF_VAL (NPIX * 25)          // 352000
#define OFF_XY  (OFF_VAL + NPIX)     // 366080

// ---------------------------------------------------------------------------
// Transpose [C, HW] -> [HW, C] per (tensor, n).  blockIdx.z: bit0 = n, bit1 = tensor
// float4 on both sides: read 16B along HW, write 16B along C.
// ---------------------------------------------------------------------------
__global__ __launch_bounds__(256) void transpose_kernel(const float* __restrict__ f1,
                                                        const float* __restrict__ f2,
                                                        float* __restrict__ f1t,
                                                        float* __restrict__ f2t) {
    __shared__ float tile[64][65];
    const int z = blockIdx.z;
    const int n = z & 1;
    const float* __restrict__ src = (z & 2) ? f2 : f1;
    float* __restrict__ dst = (z & 2) ? f2t : f1t;
    src += (size_t)n * C_ * HW_;
    dst += (size_t)n * C_ * HW_;

    const int p0 = blockIdx.x * 64;   // HW_ = 110 * 64, exact
    const int c0 = blockIdx.y * 64;   // C_  = 4 * 64, exact
    const int q = threadIdx.x & 15;   // float4 index within 64-float row
    const int r = threadIdx.x >> 4;   // 0..15

    // Read: row (c0+rr), 16 lanes x float4 = 256B contiguous per cluster.
    #pragma unroll
    for (int rr = r; rr < 64; rr += 16) {
        const float4 v = *(const float4*)(src + (size_t)(c0 + rr) * HW_ + p0 + q * 4);
        tile[rr][q * 4 + 0] = v.x;
        tile[rr][q * 4 + 1] = v.y;
        tile[rr][q * 4 + 2] = v.z;
        tile[rr][q * 4 + 3] = v.w;
    }
    __syncthreads();

    // Write: pixel (p0+pr), 16 lanes (q) x float4 = 256B contiguous along C.
    #pragma unroll
    for (int j = 0; j < 4; ++j) {
        const int pr = r + 16 * j;
        float4 v;
        v.x = tile[q * 4 + 0][pr];
        v.y = tile[q * 4 + 1][pr];
        v.z = tile[q * 4 + 2][pr];
        v.w = tile[q * 4 + 3][pr];
        *(float4*)(dst + (size_t)(p0 + pr) * C_ + c0 + q * 4) = v;
    }
}

__device__ __forceinline__ float dot4(const float4 a, const float4 b) {
    return a.x * b.x + a.y * b.y + a.z * b.z + a.w * b.w;
}

// ---------------------------------------------------------------------------
// Main kernel: 1 wave per pixel. 64 lanes = 4 sample-groups x 16 c-chunks.
// 9 passes of 4 samples; each 16-lane cluster streams one f2t row coalesced
// (16 x 16B = 256B contiguous), reduces over cgrp with 4 shfl_xor steps.
// ---------------------------------------------------------------------------
__global__ __launch_bounds__(256) void costvol_kernel(const float* __restrict__ flow,
                                                      const float* __restrict__ f1t,
                                                      const float* __restrict__ f2t,
                                                      float* __restrict__ out) {
    __shared__ float Dsh[4][36];

    const int wv   = threadIdx.x >> 6;
    const int lane = threadIdx.x & 63;
    const int sgrp = lane >> 4;     // 0..3  sample slot within pass
    const int cgrp = lane & 15;     // 0..15 channel chunk (16 floats each)
    const int pix  = blockIdx.x * 4 + wv;
    const int n    = pix / HW_;
    const int rem  = pix - n * HW_;
    const int h    = rem >> 7;                // W_ = 128
    const int w    = rem & (W_ - 1);

    // f1 fragment: 16 consecutive channels in registers.
    const float4* __restrict__ arow = (const float4*)(f1t + (size_t)pix * C_) + cgrp * 4;
    const float4 a0 = arow[0], a1 = arow[1], a2 = arow[2], a3 = arow[3];

    const float fx = flow[((size_t)(n * 2 + 0) * H_ + h) * W_ + w];
    const float fy = flow[((size_t)(n * 2 + 1) * H_ + h) * W_ + w];
    const float cx = (float)w + fx;
    const float cy = (float)h + fy;
    const float x0f = floorf(cx), y0f = floorf(cy);
    const float wx = cx - x0f,   wy = cy - y0f;
    const int ix0 = (int)x0f,    iy0 = (int)y0f;

    const float4* __restrict__ f2base =
        (const float4*)(f2t + (size_t)n * HW_ * C_);

    #pragma unroll
    for (int p = 0; p < 9; ++p) {
        const int s  = p * 4 + sgrp;
        const int ly = s / 6, lx = s - ly * 6;
        const int sy = iy0 - 2 + ly;
        const int sx = ix0 - 2 + lx;
        float part = 0.f;
        if (sy >= 0 && sy < H_ && sx >= 0 && sx < W_) {
            const float4* __restrict__ b =
                f2base + (size_t)(sy * W_ + sx) * (C_ / 4) + cgrp * 4;
            part = dot4(a0, b[0]) + dot4(a1, b[1]) + dot4(a2, b[2]) + dot4(a3, b[3]);
        }
        part += __shfl_xor(part, 1, 64);
        part += __shfl_xor(part, 2, 64);
        part += __shfl_xor(part, 4, 64);
        part += __shfl_xor(part, 8, 64);
        if (cgrp == 0) Dsh[wv][s] = part;
    }
    __syncthreads();   // Dsh visible

    float cv = 0.f;
    if (lane < 25) {
        const int i = lane / 5, j = lane - i * 5;      // i -> dy, j -> dx
        const float D00 = Dsh[wv][i * 6 + j];
        const float D01 = Dsh[wv][i * 6 + j + 1];
        const float D10 = Dsh[wv][i * 6 + j + 6];
        const float D11 = Dsh[wv][i * 6 + j + 7];
        cv = (1.f - wx) * (1.f - wy) * D00 + wx * (1.f - wy) * D01
           + (1.f - wx) * wy * D10 + wx * wy * D11;
        out[OFF_CV + (size_t)pix * 25 + lane] = cv;
    }

    // WTA: max with first-occurrence tie-break (matches np/jnp argmax).
    float v  = (lane < 25) ? cv : -3.4e38f;
    int  idx = (lane < 25) ? lane : 25;
    #pragma unroll
    for (int off = 16; off >= 1; off >>= 1) {
        const float v2 = __shfl_down(v, off, 32);
        const int   i2 = __shfl_down(idx, off, 32);
        if (v2 > v || (v2 == v && i2 < idx)) { v = v2; idx = i2; }
    }
    if (lane == 0) {
        out[OFF_VAL + pix] = v;
        out[OFF_XY + pix]        = (float)(idx % 5);   // x
        out[OFF_XY + NPIX + pix] = (float)(idx / 5);   // y
    }
}

// ---------------------------------------------------------------------------
extern "C" void kernel_launch(void* const* d_in, const int* in_sizes, int n_in,
                              void* d_out, int out_size, void* d_ws, size_t ws_size,
                              hipStream_t stream) {
    const float* flow = (const float*)d_in[0];
    const float* f1   = (const float*)d_in[1];
    const float* f2   = (const float*)d_in[2];
    float* out = (float*)d_out;

    float* f1t = (float*)d_ws;                       // [N, HW, C]
    float* f2t = f1t + (size_t)N_ * HW_ * C_;        // [N, HW, C]

    transpose_kernel<<<dim3(HW_ / 64, C_ / 64, 4), 256, 0, stream>>>(f1, f2, f1t, f2t);
    costvol_kernel<<<dim3(NPIX / 4), 256, 0, stream>>>(flow, f1t, f2t, out);
}

// Round 4
// 111.688 us; speedup vs baseline: 1.3553x; 1.0347x over previous
//
#include <hip/hip_runtime.h>

#define N_   2
#define C_   256
#define H_   55
#define W_   128
#define HW_  (H_ * W_)      // 7040
#define NPIX (N_ * HW_)     // 14080
#define NBLK (NPIX / 4)     // 3520 = 8 * 440 blocks
#define BPX  (NBLK / 8)     // 440 blocks per XCD band

#define OFF_CV  0
#define OFF_VAL (NPIX * 25)          // 352000
#define OFF_XY  (OFF_VAL + NPIX)     // 366080

// ---------------------------------------------------------------------------
// Transpose f2 only: [C, HW] -> [HW, C] per n.  blockIdx.z = n.
// float4 on both sides: read 16B along HW, write 16B along C.
// ---------------------------------------------------------------------------
__global__ __launch_bounds__(256) void transpose_f2(const float* __restrict__ f2,
                                                    float* __restrict__ f2t) {
    __shared__ float tile[64][65];
    const int n = blockIdx.z;
    const float* __restrict__ src = f2 + (size_t)n * C_ * HW_;
    float* __restrict__ dst = f2t + (size_t)n * HW_ * C_;

    const int p0 = blockIdx.x * 64;   // HW_ = 110 * 64, exact
    const int c0 = blockIdx.y * 64;   // C_  = 4 * 64, exact
    const int q = threadIdx.x & 15;   // float4 index within 64-float row
    const int r = threadIdx.x >> 4;   // 0..15

    #pragma unroll
    for (int rr = r; rr < 64; rr += 16) {
        const float4 v = *(const float4*)(src + (size_t)(c0 + rr) * HW_ + p0 + q * 4);
        tile[rr][q * 4 + 0] = v.x;
        tile[rr][q * 4 + 1] = v.y;
        tile[rr][q * 4 + 2] = v.z;
        tile[rr][q * 4 + 3] = v.w;
    }
    __syncthreads();

    #pragma unroll
    for (int j = 0; j < 4; ++j) {
        const int pr = r + 16 * j;
        float4 v;
        v.x = tile[q * 4 + 0][pr];
        v.y = tile[q * 4 + 1][pr];
        v.z = tile[q * 4 + 2][pr];
        v.w = tile[q * 4 + 3][pr];
        *(float4*)(dst + (size_t)(p0 + pr) * C_ + c0 + q * 4) = v;
    }
}

__device__ __forceinline__ float dot4(const float4 a, const float4 b) {
    return a.x * b.x + a.y * b.y + a.z * b.z + a.w * b.w;
}

// ---------------------------------------------------------------------------
// Main kernel: 1 wave per pixel, 4 pixels per block.
// XCD-band swizzle: block b -> xcd b%8 processes contiguous pixel band so each
// XCD's gather working set (~3.1MB incl. halo) stays L2-resident.
// f1 staged directly from [C,HW] layout (no f1 transpose needed).
// ---------------------------------------------------------------------------
__global__ __launch_bounds__(256) void costvol_kernel(const float* __restrict__ flow,
                                                      const float* __restrict__ f1,
                                                      const float* __restrict__ f2t,
                                                      float* __restrict__ out) {
    __shared__ float f1sh[4][C_];
    __shared__ float Dsh[4][36];

    const int b    = blockIdx.x;
    const int xcd  = b & 7;
    const int k    = b >> 3;                  // 0..439
    const int pix0 = (xcd * BPX + k) * 4;     // bijective; bands of 1760 pixels
    const int n     = pix0 / HW_;             // bands never straddle n (7040 = 4*1760)
    const int prem0 = pix0 - n * HW_;

    // Stage f1[:, pix0..pix0+3]: thread t reads 16B of channel t (4 pixels).
    {
        const int t = threadIdx.x;
        const float4 v = *(const float4*)(f1 + ((size_t)n * C_ + t) * HW_ + prem0);
        f1sh[0][t] = v.x;
        f1sh[1][t] = v.y;
        f1sh[2][t] = v.z;
        f1sh[3][t] = v.w;
    }

    const int wv   = threadIdx.x >> 6;
    const int lane = threadIdx.x & 63;
    const int sgrp = lane >> 4;     // 0..3  sample slot within pass
    const int cgrp = lane & 15;     // 0..15 channel chunk (16 floats each)
    const int pix  = pix0 + wv;
    const int rem  = prem0 + wv;
    const int h    = rem >> 7;                // W_ = 128
    const int w    = rem & (W_ - 1);

    const float fx = flow[((size_t)(n * 2 + 0) * H_ + h) * W_ + w];
    const float fy = flow[((size_t)(n * 2 + 1) * H_ + h) * W_ + w];
    const float cx = (float)w + fx;
    const float cy = (float)h + fy;
    const float x0f = floorf(cx), y0f = floorf(cy);
    const float wx = cx - x0f,   wy = cy - y0f;
    const int ix0 = (int)x0f,    iy0 = (int)y0f;

    __syncthreads();   // f1sh visible

    // f1 fragment: 16 consecutive channels in registers (from LDS).
    const float4* __restrict__ arow = (const float4*)&f1sh[wv][cgrp * 16];
    const float4 a0 = arow[0], a1 = arow[1], a2 = arow[2], a3 = arow[3];

    const float4* __restrict__ f2base =
        (const float4*)(f2t + (size_t)n * HW_ * C_);

    #pragma unroll
    for (int p = 0; p < 9; ++p) {
        const int s  = p * 4 + sgrp;
        const int ly = s / 6, lx = s - ly * 6;
        const int sy = iy0 - 2 + ly;
        const int sx = ix0 - 2 + lx;
        float part = 0.f;
        if (sy >= 0 && sy < H_ && sx >= 0 && sx < W_) {
            const float4* __restrict__ bptr =
                f2base + (size_t)(sy * W_ + sx) * (C_ / 4) + cgrp * 4;
            part = dot4(a0, bptr[0]) + dot4(a1, bptr[1])
                 + dot4(a2, bptr[2]) + dot4(a3, bptr[3]);
        }
        part += __shfl_xor(part, 1, 64);
        part += __shfl_xor(part, 2, 64);
        part += __shfl_xor(part, 4, 64);
        part += __shfl_xor(part, 8, 64);
        if (cgrp == 0) Dsh[wv][s] = part;
    }
    __syncthreads();   // Dsh visible

    float cv = 0.f;
    if (lane < 25) {
        const int i = lane / 5, j = lane - i * 5;      // i -> dy, j -> dx
        const float D00 = Dsh[wv][i * 6 + j];
        const float D01 = Dsh[wv][i * 6 + j + 1];
        const float D10 = Dsh[wv][i * 6 + j + 6];
        const float D11 = Dsh[wv][i * 6 + j + 7];
        cv = (1.f - wx) * (1.f - wy) * D00 + wx * (1.f - wy) * D01
           + (1.f - wx) * wy * D10 + wx * wy * D11;
        out[OFF_CV + (size_t)pix * 25 + lane] = cv;
    }

    // WTA: max with first-occurrence tie-break (matches np/jnp argmax).
    float v  = (lane < 25) ? cv : -3.4e38f;
    int  idx = (lane < 25) ? lane : 25;
    #pragma unroll
    for (int off = 16; off >= 1; off >>= 1) {
        const float v2 = __shfl_down(v, off, 32);
        const int   i2 = __shfl_down(idx, off, 32);
        if (v2 > v || (v2 == v && i2 < idx)) { v = v2; idx = i2; }
    }
    if (lane == 0) {
        out[OFF_VAL + pix] = v;
        out[OFF_XY + pix]        = (float)(idx % 5);   // x
        out[OFF_XY + NPIX + pix] = (float)(idx / 5);   // y
    }
}

// ---------------------------------------------------------------------------
extern "C" void kernel_launch(void* const* d_in, const int* in_sizes, int n_in,
                              void* d_out, int out_size, void* d_ws, size_t ws_size,
                              hipStream_t stream) {
    const float* flow = (const float*)d_in[0];
    const float* f1   = (const float*)d_in[1];
    const float* f2   = (const float*)d_in[2];
    float* out = (float*)d_out;

    float* f2t = (float*)d_ws;                       // [N, HW, C]

    transpose_f2<<<dim3(HW_ / 64, C_ / 64, N_), 256, 0, stream>>>(f2, f2t);
    costvol_kernel<<<dim3(NBLK), 256, 0, stream>>>(flow, f1, f2t, out);
}

// Round 5
// 103.511 us; speedup vs baseline: 1.4624x; 1.0790x over previous
//
#include <hip/hip_runtime.h>

#define N_   2
#define C_   256
#define H_   55
#define W_   128
#define HW_  (H_ * W_)      // 7040
#define NPIX (N_ * HW_)     // 14080
#define PB   16             // pixels per block
#define PW   4              // pixels per wave
#define NBLK (NPIX / PB)    // 880 = 8 * 110
#define BPX  (NBLK / 8)     // 110 blocks per XCD band
#define F1LD 260            // padded leading dim (keeps 16B align + conflict-free banks)

#define OFF_CV  0
#define OFF_VAL (NPIX * 25)          // 352000
#define OFF_XY  (OFF_VAL + NPIX)     // 366080

// ---------------------------------------------------------------------------
// Transpose f2 only: [C, HW] -> [HW, C] per n.  blockIdx.z = n.
// ---------------------------------------------------------------------------
__global__ __launch_bounds__(256) void transpose_f2(const float* __restrict__ f2,
                                                    float* __restrict__ f2t) {
    __shared__ float tile[64][65];
    const int n = blockIdx.z;
    const float* __restrict__ src = f2 + (size_t)n * C_ * HW_;
    float* __restrict__ dst = f2t + (size_t)n * HW_ * C_;

    const int p0 = blockIdx.x * 64;   // HW_ = 110 * 64, exact
    const int c0 = blockIdx.y * 64;   // C_  = 4 * 64, exact
    const int q = threadIdx.x & 15;
    const int r = threadIdx.x >> 4;

    #pragma unroll
    for (int rr = r; rr < 64; rr += 16) {
        const float4 v = *(const float4*)(src + (size_t)(c0 + rr) * HW_ + p0 + q * 4);
        tile[rr][q * 4 + 0] = v.x;
        tile[rr][q * 4 + 1] = v.y;
        tile[rr][q * 4 + 2] = v.z;
        tile[rr][q * 4 + 3] = v.w;
    }
    __syncthreads();

    #pragma unroll
    for (int j = 0; j < 4; ++j) {
        const int pr = r + 16 * j;
        float4 v;
        v.x = tile[q * 4 + 0][pr];
        v.y = tile[q * 4 + 1][pr];
        v.z = tile[q * 4 + 2][pr];
        v.w = tile[q * 4 + 3][pr];
        *(float4*)(dst + (size_t)(p0 + pr) * C_ + c0 + q * 4) = v;
    }
}

__device__ __forceinline__ float dot4(const float4 a, const float4 b) {
    return a.x * b.x + a.y * b.y + a.z * b.z + a.w * b.w;
}

// ---------------------------------------------------------------------------
// Main kernel: 16 consecutive pixels per block (all in one h-row), 4 waves x
// 4 pixels each. XCD-band swizzle keeps each XCD's gather set (~3MB) in its L2.
// f1 staged coalesced (float4 across 4 consecutive pixels) into padded LDS.
// Lane role: sgrp = lane>>4 (sample slot), cgrp = lane&15 (channel chunk).
// Channel assignment c = q*64 + cgrp*4 makes every f2 gather instruction a
// dense 256B contiguous segment.
// ---------------------------------------------------------------------------
__global__ __launch_bounds__(256) void costvol_kernel(const float* __restrict__ flow,
                                                      const float* __restrict__ f1,
                                                      const float* __restrict__ f2t,
                                                      float* __restrict__ out) {
    __shared__ float f1sh[PB][F1LD];   // ~16.6 KB
    __shared__ float Dsh[4][36];

    const int b    = blockIdx.x;
    const int xcd  = b & 7;
    const int kk   = b >> 3;
    const int pix0 = (xcd * BPX + kk) * PB;   // bijective; 1760-pixel bands per XCD
    const int n     = pix0 / HW_;             // bands never straddle n
    const int prem0 = pix0 - n * HW_;
    const int h     = prem0 >> 7;             // whole block in one h-row (128/16)
    const int w0    = prem0 & (W_ - 1);

    // Stage f1[*, pix0..pix0+15]: lane reads float4 = 4 consecutive pixels of
    // channel c. Per instr: 16 segments x 64B, fully contiguous & consumed.
    // LDS store bank = (16*px4 + 4i + c) % 32 -> 2-way (free).
    {
        const int px4   = threadIdx.x & 3;
        const int cbase = threadIdx.x >> 2;      // 0..63
        #pragma unroll
        for (int it = 0; it < 4; ++it) {
            const int c = cbase + it * 64;
            const float4 v = *(const float4*)(f1 + ((size_t)n * C_ + c) * HW_ + prem0 + px4 * 4);
            f1sh[px4 * 4 + 0][c] = v.x;
            f1sh[px4 * 4 + 1][c] = v.y;
            f1sh[px4 * 4 + 2][c] = v.z;
            f1sh[px4 * 4 + 3][c] = v.w;
        }
    }
    __syncthreads();

    const int wv   = threadIdx.x >> 6;
    const int lane = threadIdx.x & 63;
    const int sgrp = lane >> 4;     // 0..3  sample slot within pass
    const int cgrp = lane & 15;     // 0..15 channel chunk

    const float4* __restrict__ f2base = (const float4*)(f2t + (size_t)n * HW_ * C_);
    const float* __restrict__ flown   = flow + (size_t)n * 2 * HW_;

    for (int pp = 0; pp < PW; ++pp) {
        const int pl  = wv * PW + pp;          // local pixel 0..15
        const int pix = pix0 + pl;
        const int w   = w0 + pl;

        const float fx = flown[h * W_ + w];
        const float fy = flown[HW_ + h * W_ + w];
        const float cx = (float)w + fx;
        const float cy = (float)h + fy;
        const float x0f = floorf(cx), y0f = floorf(cy);
        const float wx = cx - x0f, wy = cy - y0f;
        const int ix0 = (int)x0f, iy0 = (int)y0f;

        // f1 fragment: channels {q*64 + cgrp*4 .. +3}, q=0..3. Bank: 4*(pl+cgrp)
        // -> 2-way across cgrp, broadcast across sgrp (free).
        const float* fr = &f1sh[pl][cgrp * 4];
        const float4 a0 = *(const float4*)(fr);
        const float4 a1 = *(const float4*)(fr + 64);
        const float4 a2 = *(const float4*)(fr + 128);
        const float4 a3 = *(const float4*)(fr + 192);

        #pragma unroll
        for (int p = 0; p < 9; ++p) {
            const int s  = p * 4 + sgrp;
            const int ly = s / 6, lx = s - ly * 6;   // loop-invariant over pp (LICM)
            const int sy = iy0 - 2 + ly;
            const int sx = ix0 - 2 + lx;
            float part = 0.f;
            if (sy >= 0 && sy < H_ && sx >= 0 && sx < W_) {
                const float4* __restrict__ bp =
                    f2base + (size_t)(sy * W_ + sx) * (C_ / 4) + cgrp;
                part = dot4(a0, bp[0]) + dot4(a1, bp[16])
                     + dot4(a2, bp[32]) + dot4(a3, bp[48]);
            }
            part += __shfl_xor(part, 1, 64);
            part += __shfl_xor(part, 2, 64);
            part += __shfl_xor(part, 4, 64);
            part += __shfl_xor(part, 8, 64);
            if (cgrp == 0) Dsh[wv][s] = part;   // Dsh is wave-private
        }
        __builtin_amdgcn_wave_barrier();   // order Dsh writes before reads (same wave)

        float cv = 0.f;
        if (lane < 25) {
            const int i = lane / 5, j = lane - i * 5;   // i -> dy, j -> dx
            const float D00 = Dsh[wv][i * 6 + j];
            const float D01 = Dsh[wv][i * 6 + j + 1];
            const float D10 = Dsh[wv][i * 6 + j + 6];
            const float D11 = Dsh[wv][i * 6 + j + 7];
            cv = (1.f - wx) * (1.f - wy) * D00 + wx * (1.f - wy) * D01
               + (1.f - wx) * wy * D10 + wx * wy * D11;
            out[OFF_CV + (size_t)pix * 25 + lane] = cv;
        }

        // WTA: max with first-occurrence tie-break (matches np/jnp argmax).
        float v  = (lane < 25) ? cv : -3.4e38f;
        int  idx = (lane < 25) ? lane : 25;
        #pragma unroll
        for (int off = 16; off >= 1; off >>= 1) {
            const float v2 = __shfl_down(v, off, 32);
            const int   i2 = __shfl_down(idx, off, 32);
            if (v2 > v || (v2 == v && i2 < idx)) { v = v2; idx = i2; }
        }
        if (lane == 0) {
            out[OFF_VAL + pix] = v;
            out[OFF_XY + pix]        = (float)(idx % 5);   // x
            out[OFF_XY + NPIX + pix] = (float)(idx / 5);   // y
        }
        __builtin_amdgcn_wave_barrier();   // keep next iter's Dsh writes behind reads
    }
}

// ---------------------------------------------------------------------------
extern "C" void kernel_launch(void* const* d_in, const int* in_sizes, int n_in,
                              void* d_out, int out_size, void* d_ws, size_t ws_size,
                              hipStream_t stream) {
    const float* flow = (const float*)d_in[0];
    const float* f1   = (const float*)d_in[1];
    const float* f2   = (const float*)d_in[2];
    float* out = (float*)d_out;

    float* f2t = (float*)d_ws;                       // [N, HW, C]

    transpose_f2<<<dim3(HW_ / 64, C_ / 64, N_), 256, 0, stream>>>(f2, f2t);
    costvol_kernel<<<dim3(NBLK), 256, 0, stream>>>(flow, f1, f2t, out);
}